// Round 7
// baseline (2057.061 us; speedup 1.0000x reference)
//
#include <hip/hip_runtime.h>
#include <hip/hip_bf16.h>
#include <stdint.h>

// ---------------------------------------------------------------------------
// QLoRALinear: out = x @ (NF4dq(codes,absmax) + 2*A@B)^T + bias
// R7: GEMM = R3's 4-phase 256x256 schedule but SINGLE-buffered (64KB LDS ->
//     2 blocks/CU). Quarter-granular in-place rotation:
//       stage {A0',B0'}@ph2, {B1'}@ph3, {A1'}@ph4
//       waits  vmcnt(2)@ph1, vmcnt(4|0)@ph2, vmcnt(4|0)@ph4
//       lgkmcnt(0) before BAR of every read-phase (WAR: ds_read vs next DMA).
//     Queue proof (steady, 2 loads per STAGE):
//       enter ph1: [B1(g),A1(g)]=4 ; ph1 vmcnt(2) drains B1(g)
//       ph2 +A0',B0' =6 ; vmcnt(4) drains A1(g)
//       ph3 +B1' =6 ; no wait      ; ph4 +A1' =8 ; vmcnt(4) drains A0',B0'
//     Depth: every quarter issued 2 phases before its drain deadline.
//     Prep = R3's fused kernel verbatim.
// ---------------------------------------------------------------------------

typedef __bf16 bf16x8 __attribute__((ext_vector_type(8)));
typedef float  f32x4  __attribute__((ext_vector_type(4)));
typedef unsigned short u16x8 __attribute__((ext_vector_type(8)));

__constant__ float NF4_TAB[16] = {
    -1.0f, -0.6961928009986877f, -0.5250730514526367f, -0.39491748809814453f,
    -0.28444138169288635f, -0.18477343022823334f, -0.09105003625154495f, 0.0f,
    0.07958029955625534f, 0.16093020141124725f, 0.24611230194568634f,
    0.33791524171829224f, 0.44070982933044434f, 0.5626170039176941f,
    0.7229568362236023f, 1.0f};

__device__ __forceinline__ unsigned short f2bf(float f) {
    unsigned int u = __float_as_uint(f);
    u += 0x7FFFu + ((u >> 16) & 1u);
    return (unsigned short)(u >> 16);
}

// ---- fused prep (R3 verbatim): [0,nCvt): x->bf16; [nCvt,..): build W_eff ---
__global__ __launch_bounds__(256) void prep_kernel(
    const float* __restrict__ x, unsigned short* __restrict__ xb, int n8, int nCvt,
    const int* __restrict__ codes, const float* __restrict__ absmax,
    const float* __restrict__ lA, const float* __restrict__ lB,
    unsigned short* __restrict__ W, int O, int I, int nIb) {
    if ((int)blockIdx.x < nCvt) {
        int i = blockIdx.x * 256 + threadIdx.x;
        if (i >= n8) return;
        const float4* p = (const float4*)x + (long)i * 2;
        float4 a = p[0], b = p[1];
        u16x8 o;
        o[0] = f2bf(a.x); o[1] = f2bf(a.y); o[2] = f2bf(a.z); o[3] = f2bf(a.w);
        o[4] = f2bf(b.x); o[5] = f2bf(b.y); o[6] = f2bf(b.z); o[7] = f2bf(b.w);
        *((u16x8*)xb + i) = o;
    } else {
        const int b2 = blockIdx.x - nCvt;
        const int o  = b2 / nIb;
        const int i0 = (b2 - o * nIb) * 2048 + threadIdx.x * 8;
        float bo[8];
#pragma unroll
        for (int r = 0; r < 8; ++r) bo[r] = lB[(long)r * O + o] * 2.0f;
        const long base = (long)o * I + i0;
        const int4* cp = (const int4*)(codes + base);
        int4 c0 = cp[0], c1 = cp[1];
        const float am = absmax[o * (I >> 6) + (i0 >> 6)];
        int cc[8] = {c0.x, c0.y, c0.z, c0.w, c1.x, c1.y, c1.z, c1.w};
        u16x8 ov;
#pragma unroll
        for (int j = 0; j < 8; ++j) {
            const float4* ap = (const float4*)(lA + (long)(i0 + j) * 8);
            float4 a0 = ap[0], a1 = ap[1];
            float w = NF4_TAB[cc[j] & 15] * am;
            w += a0.x * bo[0] + a0.y * bo[1] + a0.z * bo[2] + a0.w * bo[3]
               + a1.x * bo[4] + a1.y * bo[5] + a1.z * bo[6] + a1.w * bo[7];
            ov[j] = f2bf(w);
        }
        *(u16x8*)(W + base) = ov;
    }
}

// ---- main GEMM: 256x256 tile, BK=64, 8 waves, 4-phase, single 64KB buffer --
#define BM 256
#define BN 256
#define BK 64

#define GLOAD16(g, s) __builtin_amdgcn_global_load_lds(                     \
    (const __attribute__((address_space(1))) void*)(g),                     \
    (__attribute__((address_space(3))) void*)(s), 16, 0, 0)

#define STAGE(ptr, ldsbase) do {                                            \
    GLOAD16((ptr), (char*)(ldsbase) + ldsW);                                \
    GLOAD16((ptr) + SK, (char*)(ldsbase) + 8192 + ldsW); } while (0)

#define BAR() do { asm volatile("" ::: "memory");                           \
    __builtin_amdgcn_s_barrier(); asm volatile("" ::: "memory"); } while (0)

#define MFMA_QUAD(H, KQ, BREG)                                              \
    _Pragma("unroll") for (int mi = 0; mi < 4; ++mi)                        \
    _Pragma("unroll") for (int ni = 0; ni < 2; ++ni) {                      \
        acc[H][KQ][mi][ni] = __builtin_amdgcn_mfma_f32_16x16x32_bf16(       \
            a[mi][0], BREG[ni][0], acc[H][KQ][mi][ni], 0, 0, 0);            \
        acc[H][KQ][mi][ni] = __builtin_amdgcn_mfma_f32_16x16x32_bf16(       \
            a[mi][1], BREG[ni][1], acc[H][KQ][mi][ni], 0, 0, 0); }

__global__ __launch_bounds__(512, 4) void gemm_kernel(
    const unsigned short* __restrict__ A,   // [M][K] bf16 bits
    const unsigned short* __restrict__ Bm,  // [N][K] bf16 bits
    const float* __restrict__ bias,
    float* __restrict__ out, int M, int N, int K, int gx, int gy) {
    // regions: A0 [0,16K) rows 0-127 | A1 [16K,32K) rows 128-255
    //          B0 [32K,48K)          | B1 [48K,64K)
    __shared__ char lds[65536];

    // ---- XCD-aware block swizzle ------------------------------------------
    int bx, by;
    {
        const int bid = blockIdx.x;
        if ((gx & 7) == 0 && (gy & 7) == 0 && ((gx >> 3) * (gy >> 3)) == 8) {
            const int xcd = bid & 7, loc = bid >> 3;
            const int cxs = gx >> 3;
            const int cr = xcd / cxs, cc = xcd - cr * cxs;
            by = cr * 8 + (loc >> 3);
            bx = cc * 8 + (loc & 7);
        } else if (((gx * gy) & 7) == 0) {
            const int q = (gx * gy) >> 3;
            const int id = (bid & 7) * q + (bid >> 3);
            bx = id % gx; by = id / gx;
        } else { bx = bid % gx; by = bid / gx; }
    }

    const int t = threadIdx.x;
    const int w = t >> 6, l = t & 63;
    const int wr = w >> 2, wc = w & 3;
    const long mB = (long)by * BM;
    const long nB = (long)bx * BN;
    const int NT = K / BK;

    // staging constants (layout identical to R3: linear dest, src-swizzled)
    const int sRow = w * 8 + (l >> 3);
    const int sCol = ((l & 7) ^ (l >> 3)) << 3;
    const int ldsW = w * 1024;
    const long SK = 64L * K;
    const long HK = 128L * K;
    const unsigned short* gA = A  + (mB + sRow) * K + sCol;
    const unsigned short* gB = Bm + (nB + sRow) * K + sCol;

    // rolling staging sources: at tile g we stage tile (g+1)
    const unsigned short* pA0 = gA + BK;
    const unsigned short* pA1 = gA + HK + BK;
    const unsigned short* pB0 = gB + BK;
    const unsigned short* pB1 = gB + HK + BK;

    const int fr = l & 15;
    const int aoff0 = fr * 128 + ((((l >> 4)) ^ (l & 7)) << 4);
    const int aoff1 = fr * 128 + (((4 + (l >> 4)) ^ (l & 7)) << 4);

    f32x4 acc[2][2][4][2];
#pragma unroll
    for (int h = 0; h < 2; ++h)
#pragma unroll
        for (int k = 0; k < 2; ++k)
#pragma unroll
            for (int mi = 0; mi < 4; ++mi)
#pragma unroll
                for (int ni = 0; ni < 2; ++ni)
                    acc[h][k][mi][ni] = (f32x4){0.f, 0.f, 0.f, 0.f};

    // ---- prologue: tile0 all quarters; full drain --------------------------
    STAGE(gA,      lds + 0);
    STAGE(gA + HK, lds + 16384);
    STAGE(gB,      lds + 32768);
    STAGE(gB + HK, lds + 49152);
    asm volatile("s_waitcnt vmcnt(0)" ::: "memory");
    BAR();

    bf16x8 a[4][2], b0[2][2], b1[2][2];
    const char* Ab = lds + wr * 8192;           // + h*16384 + mi*2048
    const char* Bb = lds + 32768 + wc * 4096;   // + kq*16384 + ni*2048

    for (int g = 0; g < NT; ++g) {
        const bool st = (g + 1 < NT);

        // ph1: read A0,B0 frags. drain B1(g) (issued ph3(g-1)) for ph2.
#pragma unroll
        for (int mi = 0; mi < 4; ++mi) {
            a[mi][0] = *(const bf16x8*)(Ab + mi * 2048 + aoff0);
            a[mi][1] = *(const bf16x8*)(Ab + mi * 2048 + aoff1);
        }
#pragma unroll
        for (int ni = 0; ni < 2; ++ni) {
            b0[ni][0] = *(const bf16x8*)(Bb + ni * 2048 + aoff0);
            b0[ni][1] = *(const bf16x8*)(Bb + ni * 2048 + aoff1);
        }
        asm volatile("s_waitcnt vmcnt(2)" ::: "memory");
        asm volatile("s_waitcnt lgkmcnt(0)" ::: "memory");  // A0,B0 reads done (staged ph2)
        BAR();
        __builtin_amdgcn_s_setprio(1);
        MFMA_QUAD(0, 0, b0);
        __builtin_amdgcn_s_setprio(0);

        // ph2: read B1 frags; stage A0',B0'; drain A1(g) (issued ph4(g-1)) for ph3.
#pragma unroll
        for (int ni = 0; ni < 2; ++ni) {
            b1[ni][0] = *(const bf16x8*)(Bb + 16384 + ni * 2048 + aoff0);
            b1[ni][1] = *(const bf16x8*)(Bb + 16384 + ni * 2048 + aoff1);
        }
        if (st) {
            STAGE(pA0, lds + 0);
            STAGE(pB0, lds + 32768);
            asm volatile("s_waitcnt vmcnt(4)" ::: "memory");
        } else {
            asm volatile("s_waitcnt vmcnt(0)" ::: "memory");
        }
        asm volatile("s_waitcnt lgkmcnt(0)" ::: "memory");  // B1 reads done (staged ph3)
        BAR();
        __builtin_amdgcn_s_setprio(1);
        MFMA_QUAD(0, 1, b1);
        __builtin_amdgcn_s_setprio(0);

        // ph3: read A1 frags; stage B1'. no vmcnt (ph4 reads nothing).
#pragma unroll
        for (int mi = 0; mi < 4; ++mi) {
            a[mi][0] = *(const bf16x8*)(Ab + 16384 + mi * 2048 + aoff0);
            a[mi][1] = *(const bf16x8*)(Ab + 16384 + mi * 2048 + aoff1);
        }
        if (st) STAGE(pB1, lds + 49152);
        asm volatile("s_waitcnt lgkmcnt(0)" ::: "memory");  // A1 reads done (staged ph4)
        BAR();
        __builtin_amdgcn_s_setprio(1);
        MFMA_QUAD(1, 0, b0);
        __builtin_amdgcn_s_setprio(0);

        // ph4: stage A1'; drain A0',B0' (for ph1 of g+1).
        if (st) {
            STAGE(pA1, lds + 16384);
            asm volatile("s_waitcnt vmcnt(4)" ::: "memory");
        } else {
            asm volatile("s_waitcnt vmcnt(0)" ::: "memory");
        }
        BAR();
        __builtin_amdgcn_s_setprio(1);
        MFMA_QUAD(1, 1, b1);
        __builtin_amdgcn_s_setprio(0);

        pA0 += BK; pA1 += BK; pB0 += BK; pB1 += BK;
    }

    // ---- epilogue: D mapping col=l&15, row=(l>>4)*4+r; add bias ------------
    const int r4 = (l >> 4) * 4;
#pragma unroll
    for (int kq = 0; kq < 2; ++kq) {
        float bs[2];
#pragma unroll
        for (int ni = 0; ni < 2; ++ni)
            bs[ni] = bias[nB + kq * 128 + wc * 32 + ni * 16 + fr];
#pragma unroll
        for (int h = 0; h < 2; ++h)
#pragma unroll
            for (int mi = 0; mi < 4; ++mi)
#pragma unroll
                for (int r = 0; r < 4; ++r) {
                    long row = mB + h * 128 + wr * 64 + mi * 16 + r4 + r;
                    float* op = out + row * N + nB + kq * 128 + wc * 32 + fr;
#pragma unroll
                    for (int ni = 0; ni < 2; ++ni)
                        op[ni * 16] = acc[h][kq][mi][ni][r] + bs[ni];
                }
    }
}

// ---- fallback: naive, slow, correct ---------------------------------------
__global__ void naive_kernel(const float* __restrict__ x, const int* __restrict__ codes,
                             const float* __restrict__ absmax, const float* __restrict__ bias,
                             const float* __restrict__ lA, const float* __restrict__ lB,
                             float* __restrict__ out, int M, int I, int O) {
    long idx = (long)blockIdx.x * 256 + threadIdx.x;
    if (idx >= (long)M * O) return;
    int o = (int)(idx % O);
    long m = idx / O;
    const float* xr = x + m * I;
    const int* cr = codes + (long)o * I;
    const float* ar = absmax + (long)o * (I >> 6);
    float acc = 0.f;
    float la[8] = {0, 0, 0, 0, 0, 0, 0, 0};
    for (int i = 0; i < I; ++i) {
        float xv = xr[i];
        acc += xv * NF4_TAB[cr[i] & 15] * ar[i >> 6];
        const float* av = lA + (long)i * 8;
#pragma unroll
        for (int r = 0; r < 8; ++r) la[r] += xv * av[r];
    }
    float lv = 0.f;
#pragma unroll
    for (int r = 0; r < 8; ++r) lv += la[r] * lB[(long)r * O + o];
    out[idx] = acc + bias[o] + 2.0f * lv;
}

extern "C" void kernel_launch(void* const* d_in, const int* in_sizes, int n_in,
                              void* d_out, int out_size, void* d_ws, size_t ws_size,
                              hipStream_t stream) {
    const float* x      = (const float*)d_in[0];
    const int*   codes  = (const int*)d_in[1];
    const float* absmax = (const float*)d_in[2];
    const float* bias   = (const float*)d_in[3];
    const float* lA     = (const float*)d_in[4];
    const float* lB     = (const float*)d_in[5];
    float* out = (float*)d_out;

    const int I = in_sizes[4] / 8;
    const int O = in_sizes[3];
    const int M = in_sizes[0] / I;
    const int K = I;

    const size_t need = (size_t)M * K * 2 + (size_t)O * K * 2;
    if (ws_size < need || (M % BM) || (O % BN) || (K % 2048) || (K / BK) < 2) {
        long tot = (long)M * O;
        naive_kernel<<<(int)((tot + 255) / 256), 256, 0, stream>>>(
            x, codes, absmax, bias, lA, lB, out, M, I, O);
        return;
    }

    unsigned short* xb = (unsigned short*)d_ws;
    unsigned short* wb = xb + (size_t)M * K;

    const int n8   = (M * K) / 8;
    const int nCvt = (n8 + 255) / 256;
    const int nIb  = K / 2048;
    const int nPrep = nCvt + O * nIb;
    prep_kernel<<<nPrep, 256, 0, stream>>>(x, xb, n8, nCvt,
                                           codes, absmax, lA, lB, wb, O, K, nIb);
    const int gx = O / BN, gy = M / BM;
    gemm_kernel<<<gx * gy, 512, 0, stream>>>(xb, wb, bias, out, M, O, K, gx, gy);
}

// Round 8
// 350.743 us; speedup vs baseline: 5.8649x; 5.8649x over previous
//
#include <hip/hip_runtime.h>
#include <hip/hip_bf16.h>
#include <stdint.h>

// ---------------------------------------------------------------------------
// QLoRALinear: out = x @ (NF4dq(codes,absmax) + 2*A@B)^T + bias
// R8: R7's single-buffered 64KB 4-phase schedule, but __launch_bounds__(512,2)
//     (R7's (512,4) clamped VGPR to 64 -> 10GB scratch spill traffic).
//     VGPR=116 <= 128 naturally allows 2 blocks/CU with 64KB LDS.
// ---------------------------------------------------------------------------

typedef __bf16 bf16x8 __attribute__((ext_vector_type(8)));
typedef float  f32x4  __attribute__((ext_vector_type(4)));
typedef unsigned short u16x8 __attribute__((ext_vector_type(8)));

__constant__ float NF4_TAB[16] = {
    -1.0f, -0.6961928009986877f, -0.5250730514526367f, -0.39491748809814453f,
    -0.28444138169288635f, -0.18477343022823334f, -0.09105003625154495f, 0.0f,
    0.07958029955625534f, 0.16093020141124725f, 0.24611230194568634f,
    0.33791524171829224f, 0.44070982933044434f, 0.5626170039176941f,
    0.7229568362236023f, 1.0f};

__device__ __forceinline__ unsigned short f2bf(float f) {
    unsigned int u = __float_as_uint(f);
    u += 0x7FFFu + ((u >> 16) & 1u);
    return (unsigned short)(u >> 16);
}

// ---- fused prep (R3 verbatim): [0,nCvt): x->bf16; [nCvt,..): build W_eff ---
__global__ __launch_bounds__(256) void prep_kernel(
    const float* __restrict__ x, unsigned short* __restrict__ xb, int n8, int nCvt,
    const int* __restrict__ codes, const float* __restrict__ absmax,
    const float* __restrict__ lA, const float* __restrict__ lB,
    unsigned short* __restrict__ W, int O, int I, int nIb) {
    if ((int)blockIdx.x < nCvt) {
        int i = blockIdx.x * 256 + threadIdx.x;
        if (i >= n8) return;
        const float4* p = (const float4*)x + (long)i * 2;
        float4 a = p[0], b = p[1];
        u16x8 o;
        o[0] = f2bf(a.x); o[1] = f2bf(a.y); o[2] = f2bf(a.z); o[3] = f2bf(a.w);
        o[4] = f2bf(b.x); o[5] = f2bf(b.y); o[6] = f2bf(b.z); o[7] = f2bf(b.w);
        *((u16x8*)xb + i) = o;
    } else {
        const int b2 = blockIdx.x - nCvt;
        const int o  = b2 / nIb;
        const int i0 = (b2 - o * nIb) * 2048 + threadIdx.x * 8;
        float bo[8];
#pragma unroll
        for (int r = 0; r < 8; ++r) bo[r] = lB[(long)r * O + o] * 2.0f;
        const long base = (long)o * I + i0;
        const int4* cp = (const int4*)(codes + base);
        int4 c0 = cp[0], c1 = cp[1];
        const float am = absmax[o * (I >> 6) + (i0 >> 6)];
        int cc[8] = {c0.x, c0.y, c0.z, c0.w, c1.x, c1.y, c1.z, c1.w};
        u16x8 ov;
#pragma unroll
        for (int j = 0; j < 8; ++j) {
            const float4* ap = (const float4*)(lA + (long)(i0 + j) * 8);
            float4 a0 = ap[0], a1 = ap[1];
            float w = NF4_TAB[cc[j] & 15] * am;
            w += a0.x * bo[0] + a0.y * bo[1] + a0.z * bo[2] + a0.w * bo[3]
               + a1.x * bo[4] + a1.y * bo[5] + a1.z * bo[6] + a1.w * bo[7];
            ov[j] = f2bf(w);
        }
        *(u16x8*)(W + base) = ov;
    }
}

// ---- main GEMM: 256x256 tile, BK=64, 8 waves, 4-phase, single 64KB buffer --
#define BM 256
#define BN 256
#define BK 64

#define GLOAD16(g, s) __builtin_amdgcn_global_load_lds(                     \
    (const __attribute__((address_space(1))) void*)(g),                     \
    (__attribute__((address_space(3))) void*)(s), 16, 0, 0)

#define STAGE(ptr, ldsbase) do {                                            \
    GLOAD16((ptr), (char*)(ldsbase) + ldsW);                                \
    GLOAD16((ptr) + SK, (char*)(ldsbase) + 8192 + ldsW); } while (0)

#define BAR() do { asm volatile("" ::: "memory");                           \
    __builtin_amdgcn_s_barrier(); asm volatile("" ::: "memory"); } while (0)

#define MFMA_QUAD(H, KQ, BREG)                                              \
    _Pragma("unroll") for (int mi = 0; mi < 4; ++mi)                        \
    _Pragma("unroll") for (int ni = 0; ni < 2; ++ni) {                      \
        acc[H][KQ][mi][ni] = __builtin_amdgcn_mfma_f32_16x16x32_bf16(       \
            a[mi][0], BREG[ni][0], acc[H][KQ][mi][ni], 0, 0, 0);            \
        acc[H][KQ][mi][ni] = __builtin_amdgcn_mfma_f32_16x16x32_bf16(       \
            a[mi][1], BREG[ni][1], acc[H][KQ][mi][ni], 0, 0, 0); }

__global__ __launch_bounds__(512, 2) void gemm_kernel(
    const unsigned short* __restrict__ A,   // [M][K] bf16 bits
    const unsigned short* __restrict__ Bm,  // [N][K] bf16 bits
    const float* __restrict__ bias,
    float* __restrict__ out, int M, int N, int K, int gx, int gy) {
    // regions: A0 [0,16K) rows 0-127 | A1 [16K,32K) rows 128-255
    //          B0 [32K,48K)          | B1 [48K,64K)
    __shared__ char lds[65536];

    // ---- XCD-aware block swizzle ------------------------------------------
    int bx, by;
    {
        const int bid = blockIdx.x;
        if ((gx & 7) == 0 && (gy & 7) == 0 && ((gx >> 3) * (gy >> 3)) == 8) {
            const int xcd = bid & 7, loc = bid >> 3;
            const int cxs = gx >> 3;
            const int cr = xcd / cxs, cc = xcd - cr * cxs;
            by = cr * 8 + (loc >> 3);
            bx = cc * 8 + (loc & 7);
        } else if (((gx * gy) & 7) == 0) {
            const int q = (gx * gy) >> 3;
            const int id = (bid & 7) * q + (bid >> 3);
            bx = id % gx; by = id / gx;
        } else { bx = bid % gx; by = bid / gx; }
    }

    const int t = threadIdx.x;
    const int w = t >> 6, l = t & 63;
    const int wr = w >> 2, wc = w & 3;
    const long mB = (long)by * BM;
    const long nB = (long)bx * BN;
    const int NT = K / BK;

    // staging constants (linear dest, src-swizzled)
    const int sRow = w * 8 + (l >> 3);
    const int sCol = ((l & 7) ^ (l >> 3)) << 3;
    const int ldsW = w * 1024;
    const long SK = 64L * K;
    const long HK = 128L * K;
    const unsigned short* gA = A  + (mB + sRow) * K + sCol;
    const unsigned short* gB = Bm + (nB + sRow) * K + sCol;

    // rolling staging sources: at tile g we stage tile (g+1)
    const unsigned short* pA0 = gA + BK;
    const unsigned short* pA1 = gA + HK + BK;
    const unsigned short* pB0 = gB + BK;
    const unsigned short* pB1 = gB + HK + BK;

    const int fr = l & 15;
    const int aoff0 = fr * 128 + ((((l >> 4)) ^ (l & 7)) << 4);
    const int aoff1 = fr * 128 + (((4 + (l >> 4)) ^ (l & 7)) << 4);

    f32x4 acc[2][2][4][2];
#pragma unroll
    for (int h = 0; h < 2; ++h)
#pragma unroll
        for (int k = 0; k < 2; ++k)
#pragma unroll
            for (int mi = 0; mi < 4; ++mi)
#pragma unroll
                for (int ni = 0; ni < 2; ++ni)
                    acc[h][k][mi][ni] = (f32x4){0.f, 0.f, 0.f, 0.f};

    // ---- prologue: tile0 all quarters; full drain --------------------------
    STAGE(gA,      lds + 0);
    STAGE(gA + HK, lds + 16384);
    STAGE(gB,      lds + 32768);
    STAGE(gB + HK, lds + 49152);
    asm volatile("s_waitcnt vmcnt(0)" ::: "memory");
    BAR();

    bf16x8 a[4][2], b0[2][2], b1[2][2];
    const char* Ab = lds + wr * 8192;           // + h*16384 + mi*2048
    const char* Bb = lds + 32768 + wc * 4096;   // + kq*16384 + ni*2048

    for (int g = 0; g < NT; ++g) {
        const bool st = (g + 1 < NT);

        // ph1: read A0,B0 frags. drain B1(g) (issued ph3(g-1)) for ph2.
#pragma unroll
        for (int mi = 0; mi < 4; ++mi) {
            a[mi][0] = *(const bf16x8*)(Ab + mi * 2048 + aoff0);
            a[mi][1] = *(const bf16x8*)(Ab + mi * 2048 + aoff1);
        }
#pragma unroll
        for (int ni = 0; ni < 2; ++ni) {
            b0[ni][0] = *(const bf16x8*)(Bb + ni * 2048 + aoff0);
            b0[ni][1] = *(const bf16x8*)(Bb + ni * 2048 + aoff1);
        }
        asm volatile("s_waitcnt vmcnt(2)" ::: "memory");
        asm volatile("s_waitcnt lgkmcnt(0)" ::: "memory");  // A0,B0 reads done (staged ph2)
        BAR();
        __builtin_amdgcn_s_setprio(1);
        MFMA_QUAD(0, 0, b0);
        __builtin_amdgcn_s_setprio(0);

        // ph2: read B1 frags; stage A0',B0'; drain A1(g) (issued ph4(g-1)).
#pragma unroll
        for (int ni = 0; ni < 2; ++ni) {
            b1[ni][0] = *(const bf16x8*)(Bb + 16384 + ni * 2048 + aoff0);
            b1[ni][1] = *(const bf16x8*)(Bb + 16384 + ni * 2048 + aoff1);
        }
        if (st) {
            STAGE(pA0, lds + 0);
            STAGE(pB0, lds + 32768);
            asm volatile("s_waitcnt vmcnt(4)" ::: "memory");
        } else {
            asm volatile("s_waitcnt vmcnt(0)" ::: "memory");
        }
        asm volatile("s_waitcnt lgkmcnt(0)" ::: "memory");  // B1 reads done (staged ph3)
        BAR();
        __builtin_amdgcn_s_setprio(1);
        MFMA_QUAD(0, 1, b1);
        __builtin_amdgcn_s_setprio(0);

        // ph3: read A1 frags; stage B1'. no vmcnt (ph4 reads nothing).
#pragma unroll
        for (int mi = 0; mi < 4; ++mi) {
            a[mi][0] = *(const bf16x8*)(Ab + 16384 + mi * 2048 + aoff0);
            a[mi][1] = *(const bf16x8*)(Ab + 16384 + mi * 2048 + aoff1);
        }
        if (st) STAGE(pB1, lds + 49152);
        asm volatile("s_waitcnt lgkmcnt(0)" ::: "memory");  // A1 reads done (staged ph4)
        BAR();
        __builtin_amdgcn_s_setprio(1);
        MFMA_QUAD(1, 0, b0);
        __builtin_amdgcn_s_setprio(0);

        // ph4: stage A1'; drain A0',B0' (for ph1 of g+1).
        if (st) {
            STAGE(pA1, lds + 16384);
            asm volatile("s_waitcnt vmcnt(4)" ::: "memory");
        } else {
            asm volatile("s_waitcnt vmcnt(0)" ::: "memory");
        }
        BAR();
        __builtin_amdgcn_s_setprio(1);
        MFMA_QUAD(1, 1, b1);
        __builtin_amdgcn_s_setprio(0);

        pA0 += BK; pA1 += BK; pB0 += BK; pB1 += BK;
    }

    // ---- epilogue: D mapping col=l&15, row=(l>>4)*4+r; add bias ------------
    const int r4 = (l >> 4) * 4;
#pragma unroll
    for (int kq = 0; kq < 2; ++kq) {
        float bs[2];
#pragma unroll
        for (int ni = 0; ni < 2; ++ni)
            bs[ni] = bias[nB + kq * 128 + wc * 32 + ni * 16 + fr];
#pragma unroll
        for (int h = 0; h < 2; ++h)
#pragma unroll
            for (int mi = 0; mi < 4; ++mi)
#pragma unroll
                for (int r = 0; r < 4; ++r) {
                    long row = mB + h * 128 + wr * 64 + mi * 16 + r4 + r;
                    float* op = out + row * N + nB + kq * 128 + wc * 32 + fr;
#pragma unroll
                    for (int ni = 0; ni < 2; ++ni)
                        op[ni * 16] = acc[h][kq][mi][ni][r] + bs[ni];
                }
    }
}

// ---- fallback: naive, slow, correct ---------------------------------------
__global__ void naive_kernel(const float* __restrict__ x, const int* __restrict__ codes,
                             const float* __restrict__ absmax, const float* __restrict__ bias,
                             const float* __restrict__ lA, const float* __restrict__ lB,
                             float* __restrict__ out, int M, int I, int O) {
    long idx = (long)blockIdx.x * 256 + threadIdx.x;
    if (idx >= (long)M * O) return;
    int o = (int)(idx % O);
    long m = idx / O;
    const float* xr = x + m * I;
    const int* cr = codes + (long)o * I;
    const float* ar = absmax + (long)o * (I >> 6);
    float acc = 0.f;
    float la[8] = {0, 0, 0, 0, 0, 0, 0, 0};
    for (int i = 0; i < I; ++i) {
        float xv = xr[i];
        acc += xv * NF4_TAB[cr[i] & 15] * ar[i >> 6];
        const float* av = lA + (long)i * 8;
#pragma unroll
        for (int r = 0; r < 8; ++r) la[r] += xv * av[r];
    }
    float lv = 0.f;
#pragma unroll
    for (int r = 0; r < 8; ++r) lv += la[r] * lB[(long)r * O + o];
    out[idx] = acc + bias[o] + 2.0f * lv;
}

extern "C" void kernel_launch(void* const* d_in, const int* in_sizes, int n_in,
                              void* d_out, int out_size, void* d_ws, size_t ws_size,
                              hipStream_t stream) {
    const float* x      = (const float*)d_in[0];
    const int*   codes  = (const int*)d_in[1];
    const float* absmax = (const float*)d_in[2];
    const float* bias   = (const float*)d_in[3];
    const float* lA     = (const float*)d_in[4];
    const float* lB     = (const float*)d_in[5];
    float* out = (float*)d_out;

    const int I = in_sizes[4] / 8;
    const int O = in_sizes[3];
    const int M = in_sizes[0] / I;
    const int K = I;

    const size_t need = (size_t)M * K * 2 + (size_t)O * K * 2;
    if (ws_size < need || (M % BM) || (O % BN) || (K % 2048) || (K / BK) < 2) {
        long tot = (long)M * O;
        naive_kernel<<<(int)((tot + 255) / 256), 256, 0, stream>>>(
            x, codes, absmax, bias, lA, lB, out, M, I, O);
        return;
    }

    unsigned short* xb = (unsigned short*)d_ws;
    unsigned short* wb = xb + (size_t)M * K;

    const int n8   = (M * K) / 8;
    const int nCvt = (n8 + 255) / 256;
    const int nIb  = K / 2048;
    const int nPrep = nCvt + O * nIb;
    prep_kernel<<<nPrep, 256, 0, stream>>>(x, xb, n8, nCvt,
                                           codes, absmax, lA, lB, wb, O, K, nIb);
    const int gx = O / BN, gy = M / BM;
    gemm_kernel<<<gx * gy, 512, 0, stream>>>(xb, wb, bias, out, M, O, K, gx, gy);
}

// Round 9
// 347.992 us; speedup vs baseline: 5.9112x; 1.0079x over previous
//
#include <hip/hip_runtime.h>
#include <hip/hip_bf16.h>
#include <stdint.h>

// ---------------------------------------------------------------------------
// QLoRALinear: out = x @ (NF4dq(codes,absmax) + 2*A@B)^T + bias
// R9: GEMM = R8 verbatim (single-buffered 64KB, 4-phase, 245us plateau).
//     Prep rebuilt: 6144 fat blocks, 4 independent unrolled iters/thread
//     (cvt 128B-read/64B-write per thread) -> MLP-bound, not launch-bound.
// ---------------------------------------------------------------------------

typedef __bf16 bf16x8 __attribute__((ext_vector_type(8)));
typedef float  f32x4  __attribute__((ext_vector_type(4)));
typedef unsigned short u16x8 __attribute__((ext_vector_type(8)));

__constant__ float NF4_TAB[16] = {
    -1.0f, -0.6961928009986877f, -0.5250730514526367f, -0.39491748809814453f,
    -0.28444138169288635f, -0.18477343022823334f, -0.09105003625154495f, 0.0f,
    0.07958029955625534f, 0.16093020141124725f, 0.24611230194568634f,
    0.33791524171829224f, 0.44070982933044434f, 0.5626170039176941f,
    0.7229568362236023f, 1.0f};

__device__ __forceinline__ unsigned short f2bf(float f) {
    unsigned int u = __float_as_uint(f);
    u += 0x7FFFu + ((u >> 16) & 1u);
    return (unsigned short)(u >> 16);
}

#define CVT_BLOCKS 4096
#define BLD_BLOCKS 2048

// ---- prep: [0,CVT): x->bf16, 4x8 elems/thread; [CVT,..): W_eff 4x8/thread --
__global__ __launch_bounds__(256) void prep_kernel(
    const float* __restrict__ x, unsigned short* __restrict__ xb, int n8,
    const int* __restrict__ codes, const float* __restrict__ absmax,
    const float* __restrict__ lA, const float* __restrict__ lB,
    unsigned short* __restrict__ W, int O, int I, int nW8) {
    if ((int)blockIdx.x < CVT_BLOCKS) {
        const int base = blockIdx.x * 256 + threadIdx.x;
        const int stride = CVT_BLOCKS * 256;
#pragma unroll
        for (int k = 0; k < 4; ++k) {
            const int i = base + k * stride;
            if (i < n8) {
                const float4* p = (const float4*)x + (long)i * 2;
                float4 a = p[0], b = p[1];
                u16x8 o;
                o[0] = f2bf(a.x); o[1] = f2bf(a.y); o[2] = f2bf(a.z); o[3] = f2bf(a.w);
                o[4] = f2bf(b.x); o[5] = f2bf(b.y); o[6] = f2bf(b.z); o[7] = f2bf(b.w);
                *((u16x8*)xb + i) = o;
            }
        }
    } else {
        const int base = (blockIdx.x - CVT_BLOCKS) * 256 + threadIdx.x;
        const int stride = BLD_BLOCKS * 256;
        const int gpr = I >> 3;                    // 8-elem groups per row
#pragma unroll
        for (int k = 0; k < 4; ++k) {
            const int g8 = base + k * stride;
            if (g8 < nW8) {
                const int o  = g8 / gpr;
                const int i0 = (g8 - o * gpr) << 3;
                float bo[8];
#pragma unroll
                for (int r = 0; r < 8; ++r) bo[r] = lB[(long)r * O + o] * 2.0f;
                const long bse = (long)o * I + i0;
                const int4* cp = (const int4*)(codes + bse);
                int4 c0 = cp[0], c1 = cp[1];
                const float am = absmax[o * (I >> 6) + (i0 >> 6)];
                int cc[8] = {c0.x, c0.y, c0.z, c0.w, c1.x, c1.y, c1.z, c1.w};
                u16x8 ov;
#pragma unroll
                for (int j = 0; j < 8; ++j) {
                    const float4* ap = (const float4*)(lA + (long)(i0 + j) * 8);
                    float4 a0 = ap[0], a1 = ap[1];
                    float wv = NF4_TAB[cc[j] & 15] * am;
                    wv += a0.x * bo[0] + a0.y * bo[1] + a0.z * bo[2] + a0.w * bo[3]
                        + a1.x * bo[4] + a1.y * bo[5] + a1.z * bo[6] + a1.w * bo[7];
                    ov[j] = f2bf(wv);
                }
                *(u16x8*)(W + bse) = ov;
            }
        }
    }
}

// ---- main GEMM: 256x256 tile, BK=64, 8 waves, 4-phase, single 64KB buffer --
#define BM 256
#define BN 256
#define BK 64

#define GLOAD16(g, s) __builtin_amdgcn_global_load_lds(                     \
    (const __attribute__((address_space(1))) void*)(g),                     \
    (__attribute__((address_space(3))) void*)(s), 16, 0, 0)

#define STAGE(ptr, ldsbase) do {                                            \
    GLOAD16((ptr), (char*)(ldsbase) + ldsW);                                \
    GLOAD16((ptr) + SK, (char*)(ldsbase) + 8192 + ldsW); } while (0)

#define BAR() do { asm volatile("" ::: "memory");                           \
    __builtin_amdgcn_s_barrier(); asm volatile("" ::: "memory"); } while (0)

#define MFMA_QUAD(H, KQ, BREG)                                              \
    _Pragma("unroll") for (int mi = 0; mi < 4; ++mi)                        \
    _Pragma("unroll") for (int ni = 0; ni < 2; ++ni) {                      \
        acc[H][KQ][mi][ni] = __builtin_amdgcn_mfma_f32_16x16x32_bf16(       \
            a[mi][0], BREG[ni][0], acc[H][KQ][mi][ni], 0, 0, 0);            \
        acc[H][KQ][mi][ni] = __builtin_amdgcn_mfma_f32_16x16x32_bf16(       \
            a[mi][1], BREG[ni][1], acc[H][KQ][mi][ni], 0, 0, 0); }

__global__ __launch_bounds__(512, 2) void gemm_kernel(
    const unsigned short* __restrict__ A,   // [M][K] bf16 bits
    const unsigned short* __restrict__ Bm,  // [N][K] bf16 bits
    const float* __restrict__ bias,
    float* __restrict__ out, int M, int N, int K, int gx, int gy) {
    // regions: A0 [0,16K) rows 0-127 | A1 [16K,32K) rows 128-255
    //          B0 [32K,48K)          | B1 [48K,64K)
    __shared__ char lds[65536];

    // ---- XCD-aware block swizzle ------------------------------------------
    int bx, by;
    {
        const int bid = blockIdx.x;
        if ((gx & 7) == 0 && (gy & 7) == 0 && ((gx >> 3) * (gy >> 3)) == 8) {
            const int xcd = bid & 7, loc = bid >> 3;
            const int cxs = gx >> 3;
            const int cr = xcd / cxs, cc = xcd - cr * cxs;
            by = cr * 8 + (loc >> 3);
            bx = cc * 8 + (loc & 7);
        } else if (((gx * gy) & 7) == 0) {
            const int q = (gx * gy) >> 3;
            const int id = (bid & 7) * q + (bid >> 3);
            bx = id % gx; by = id / gx;
        } else { bx = bid % gx; by = bid / gx; }
    }

    const int t = threadIdx.x;
    const int w = t >> 6, l = t & 63;
    const int wr = w >> 2, wc = w & 3;
    const long mB = (long)by * BM;
    const long nB = (long)bx * BN;
    const int NT = K / BK;

    // staging constants (linear dest, src-swizzled)
    const int sRow = w * 8 + (l >> 3);
    const int sCol = ((l & 7) ^ (l >> 3)) << 3;
    const int ldsW = w * 1024;
    const long SK = 64L * K;
    const long HK = 128L * K;
    const unsigned short* gA = A  + (mB + sRow) * K + sCol;
    const unsigned short* gB = Bm + (nB + sRow) * K + sCol;

    // rolling staging sources: at tile g we stage tile (g+1)
    const unsigned short* pA0 = gA + BK;
    const unsigned short* pA1 = gA + HK + BK;
    const unsigned short* pB0 = gB + BK;
    const unsigned short* pB1 = gB + HK + BK;

    const int fr = l & 15;
    const int aoff0 = fr * 128 + ((((l >> 4)) ^ (l & 7)) << 4);
    const int aoff1 = fr * 128 + (((4 + (l >> 4)) ^ (l & 7)) << 4);

    f32x4 acc[2][2][4][2];
#pragma unroll
    for (int h = 0; h < 2; ++h)
#pragma unroll
        for (int k = 0; k < 2; ++k)
#pragma unroll
            for (int mi = 0; mi < 4; ++mi)
#pragma unroll
                for (int ni = 0; ni < 2; ++ni)
                    acc[h][k][mi][ni] = (f32x4){0.f, 0.f, 0.f, 0.f};

    // ---- prologue: tile0 all quarters; full drain --------------------------
    STAGE(gA,      lds + 0);
    STAGE(gA + HK, lds + 16384);
    STAGE(gB,      lds + 32768);
    STAGE(gB + HK, lds + 49152);
    asm volatile("s_waitcnt vmcnt(0)" ::: "memory");
    BAR();

    bf16x8 a[4][2], b0[2][2], b1[2][2];
    const char* Ab = lds + wr * 8192;           // + h*16384 + mi*2048
    const char* Bb = lds + 32768 + wc * 4096;   // + kq*16384 + ni*2048

    for (int g = 0; g < NT; ++g) {
        const bool st = (g + 1 < NT);

        // ph1: read A0,B0 frags. drain B1(g) (issued ph3(g-1)) for ph2.
#pragma unroll
        for (int mi = 0; mi < 4; ++mi) {
            a[mi][0] = *(const bf16x8*)(Ab + mi * 2048 + aoff0);
            a[mi][1] = *(const bf16x8*)(Ab + mi * 2048 + aoff1);
        }
#pragma unroll
        for (int ni = 0; ni < 2; ++ni) {
            b0[ni][0] = *(const bf16x8*)(Bb + ni * 2048 + aoff0);
            b0[ni][1] = *(const bf16x8*)(Bb + ni * 2048 + aoff1);
        }
        asm volatile("s_waitcnt vmcnt(2)" ::: "memory");
        asm volatile("s_waitcnt lgkmcnt(0)" ::: "memory");  // A0,B0 reads done (staged ph2)
        BAR();
        __builtin_amdgcn_s_setprio(1);
        MFMA_QUAD(0, 0, b0);
        __builtin_amdgcn_s_setprio(0);

        // ph2: read B1 frags; stage A0',B0'; drain A1(g) (issued ph4(g-1)).
#pragma unroll
        for (int ni = 0; ni < 2; ++ni) {
            b1[ni][0] = *(const bf16x8*)(Bb + 16384 + ni * 2048 + aoff0);
            b1[ni][1] = *(const bf16x8*)(Bb + 16384 + ni * 2048 + aoff1);
        }
        if (st) {
            STAGE(pA0, lds + 0);
            STAGE(pB0, lds + 32768);
            asm volatile("s_waitcnt vmcnt(4)" ::: "memory");
        } else {
            asm volatile("s_waitcnt vmcnt(0)" ::: "memory");
        }
        asm volatile("s_waitcnt lgkmcnt(0)" ::: "memory");  // B1 reads done (staged ph3)
        BAR();
        __builtin_amdgcn_s_setprio(1);
        MFMA_QUAD(0, 1, b1);
        __builtin_amdgcn_s_setprio(0);

        // ph3: read A1 frags; stage B1'. no vmcnt (ph4 reads nothing).
#pragma unroll
        for (int mi = 0; mi < 4; ++mi) {
            a[mi][0] = *(const bf16x8*)(Ab + 16384 + mi * 2048 + aoff0);
            a[mi][1] = *(const bf16x8*)(Ab + 16384 + mi * 2048 + aoff1);
        }
        if (st) STAGE(pB1, lds + 49152);
        asm volatile("s_waitcnt lgkmcnt(0)" ::: "memory");  // A1 reads done (staged ph4)
        BAR();
        __builtin_amdgcn_s_setprio(1);
        MFMA_QUAD(1, 0, b0);
        __builtin_amdgcn_s_setprio(0);

        // ph4: stage A1'; drain A0',B0' (for ph1 of g+1).
        if (st) {
            STAGE(pA1, lds + 16384);
            asm volatile("s_waitcnt vmcnt(4)" ::: "memory");
        } else {
            asm volatile("s_waitcnt vmcnt(0)" ::: "memory");
        }
        BAR();
        __builtin_amdgcn_s_setprio(1);
        MFMA_QUAD(1, 1, b1);
        __builtin_amdgcn_s_setprio(0);

        pA0 += BK; pA1 += BK; pB0 += BK; pB1 += BK;
    }

    // ---- epilogue: D mapping col=l&15, row=(l>>4)*4+r; add bias ------------
    const int r4 = (l >> 4) * 4;
#pragma unroll
    for (int kq = 0; kq < 2; ++kq) {
        float bs[2];
#pragma unroll
        for (int ni = 0; ni < 2; ++ni)
            bs[ni] = bias[nB + kq * 128 + wc * 32 + ni * 16 + fr];
#pragma unroll
        for (int h = 0; h < 2; ++h)
#pragma unroll
            for (int mi = 0; mi < 4; ++mi)
#pragma unroll
                for (int r = 0; r < 4; ++r) {
                    long row = mB + h * 128 + wr * 64 + mi * 16 + r4 + r;
                    float* op = out + row * N + nB + kq * 128 + wc * 32 + fr;
#pragma unroll
                    for (int ni = 0; ni < 2; ++ni)
                        op[ni * 16] = acc[h][kq][mi][ni][r] + bs[ni];
                }
    }
}

// ---- fallback: naive, slow, correct ---------------------------------------
__global__ void naive_kernel(const float* __restrict__ x, const int* __restrict__ codes,
                             const float* __restrict__ absmax, const float* __restrict__ bias,
                             const float* __restrict__ lA, const float* __restrict__ lB,
                             float* __restrict__ out, int M, int I, int O) {
    long idx = (long)blockIdx.x * 256 + threadIdx.x;
    if (idx >= (long)M * O) return;
    int o = (int)(idx % O);
    long m = idx / O;
    const float* xr = x + m * I;
    const int* cr = codes + (long)o * I;
    const float* ar = absmax + (long)o * (I >> 6);
    float acc = 0.f;
    float la[8] = {0, 0, 0, 0, 0, 0, 0, 0};
    for (int i = 0; i < I; ++i) {
        float xv = xr[i];
        acc += xv * NF4_TAB[cr[i] & 15] * ar[i >> 6];
        const float* av = lA + (long)i * 8;
#pragma unroll
        for (int r = 0; r < 8; ++r) la[r] += xv * av[r];
    }
    float lv = 0.f;
#pragma unroll
    for (int r = 0; r < 8; ++r) lv += la[r] * lB[(long)r * O + o];
    out[idx] = acc + bias[o] + 2.0f * lv;
}

extern "C" void kernel_launch(void* const* d_in, const int* in_sizes, int n_in,
                              void* d_out, int out_size, void* d_ws, size_t ws_size,
                              hipStream_t stream) {
    const float* x      = (const float*)d_in[0];
    const int*   codes  = (const int*)d_in[1];
    const float* absmax = (const float*)d_in[2];
    const float* bias   = (const float*)d_in[3];
    const float* lA     = (const float*)d_in[4];
    const float* lB     = (const float*)d_in[5];
    float* out = (float*)d_out;

    const int I = in_sizes[4] / 8;
    const int O = in_sizes[3];
    const int M = in_sizes[0] / I;
    const int K = I;

    const size_t need = (size_t)M * K * 2 + (size_t)O * K * 2;
    if (ws_size < need || (M % BM) || (O % BN) || (K % 2048) || (K / BK) < 2) {
        long tot = (long)M * O;
        naive_kernel<<<(int)((tot + 255) / 256), 256, 0, stream>>>(
            x, codes, absmax, bias, lA, lB, out, M, I, O);
        return;
    }

    unsigned short* xb = (unsigned short*)d_ws;
    unsigned short* wb = xb + (size_t)M * K;

    const int n8  = (M * K) / 8;
    const int nW8 = (O * K) / 8;
    prep_kernel<<<CVT_BLOCKS + BLD_BLOCKS, 256, 0, stream>>>(
        x, xb, n8, codes, absmax, lA, lB, wb, O, K, nW8);
    const int gx = O / BN, gy = M / BM;
    gemm_kernel<<<gx * gy, 512, 0, stream>>>(xb, wb, bias, out, M, O, K, gx, gy);
}